// Round 3
// baseline (103.241 us; speedup 1.0000x reference)
//
#include <hip/hip_runtime.h>

// Problem constants (fixed by the reference):
//   B=4096, L=200, EMBEDDING_DIM=100, C=2 chunks of M=50, VOCAB=100000
constexpr int C_ = 2;
constexpr int M_ = 50;
constexpr int ED = 100;
constexpr float EPS = 1e-8f;

constexpr int ROWS = 128;   // rows staged per block in pass 1
constexpr int PAD  = 101;   // padded LDS row stride (floats): (101*t+e)%32 permutes in t -> conflict-free

// ---------------------------------------------------------------------------
// Pass 1: per-vocab-row statistics. alpha_c and alpha_c*proj_c depend ONLY on
// the row (u, w are constants): tbl[r] = (a0, a1, a0*dw0, a1*dw1).
// Staged through LDS so global reads are fully coalesced (contiguous float4).
// ---------------------------------------------------------------------------
__global__ __launch_bounds__(128) void row_stats_kernel(
    const float* __restrict__ emb,   // [VOCAB, 100]
    const float* __restrict__ wgt,   // [100]
    const float* __restrict__ att,   // [100] = [2,50]
    float4*      __restrict__ tbl,   // [VOCAB]
    int vocab)
{
    __shared__ float  s_rows[ROWS * PAD];  // 51.7 KB -> 3 blocks/CU
    __shared__ float2 s_uw[ED];            // (attend_u[e], weights[e])
    __shared__ float  s_su[C_];            // 1 / max(||u_c||, eps)

    const int t  = threadIdx.x;
    const int r0 = blockIdx.x * ROWS;

    if (t < ED) s_uw[t] = make_float2(att[t], wgt[t]);
    __syncthreads();
    if (t < C_) {
        float ss = 0.f;
        #pragma unroll
        for (int m = 0; m < M_; ++m) { float v = s_uw[t * M_ + m].x; ss += v * v; }
        s_su[t] = 1.0f / fmaxf(sqrtf(ss), EPS);
    }

    // Stage nrows*100 floats: contiguous float4 loads, coalesced (1 KB/wave-instr).
    const int nrows = min(ROWS, vocab - r0);
    const int nvec  = nrows * (ED / 4);
    const float4* src = reinterpret_cast<const float4*>(emb + (long long)r0 * ED);
    for (int i = t; i < nvec; i += 128) {
        const float4 v = src[i];
        const int F   = i * 4;          // flat float offset
        const int row = F / ED;         // div-by-const -> magic mul
        const int col = F - row * ED;   // col % 4 == 0, same row for all 4 elems
        float* d = &s_rows[row * PAD + col];
        d[0] = v.x; d[1] = v.y; d[2] = v.z; d[3] = v.w;
    }
    __syncthreads();

    if (t < nrows) {
        const float* row = &s_rows[t * PAD];
        float sq0 = 0.f, sq1 = 0.f, du0 = 0.f, du1 = 0.f, dw0 = 0.f, dw1 = 0.f;
        #pragma unroll
        for (int e = 0; e < M_; ++e) {
            const float x = row[e];
            const float2 uw = s_uw[e];           // broadcast, free
            sq0 += x * x; du0 = fmaf(x, uw.x, du0); dw0 = fmaf(x, uw.y, dw0);
        }
        #pragma unroll
        for (int e = M_; e < ED; ++e) {
            const float x = row[e];
            const float2 uw = s_uw[e];
            sq1 += x * x; du1 = fmaf(x, uw.x, du1); dw1 = fmaf(x, uw.y, dw1);
        }
        const float c0 = du0 / fmaxf(sqrtf(sq0), EPS) * s_su[0];
        const float c1 = du1 / fmaxf(sqrtf(sq1), EPS) * s_su[1];
        const float a0 = __expf(c0);
        const float a1 = __expf(c1);
        tbl[r0 + t] = make_float4(a0, a1, a0 * dw0, a1 * dw1);
    }
}

// ---------------------------------------------------------------------------
// Pass 2: one WAVE per batch element. out[b] = P0/A0 + P1/A1 over L gathered
// table entries (16 B each, table is L2-resident). No LDS, no __syncthreads.
// ---------------------------------------------------------------------------
__global__ __launch_bounds__(256) void attend_kernel(
    const int*    __restrict__ idx,  // [B, L]
    const float4* __restrict__ tbl,  // [VOCAB]
    float*        __restrict__ out,  // [B]
    int B, int L)
{
    const int wave = threadIdx.x >> 6;
    const int lane = threadIdx.x & 63;
    const int b    = blockIdx.x * 4 + wave;
    if (b >= B) return;

    const int* ib = idx + (long long)b * L;
    float a0 = 0.f, a1 = 0.f, ap0 = 0.f, ap1 = 0.f;
    #pragma unroll 4
    for (int l = lane; l < L; l += 64) {       // coalesced idx read, L2-hit gather
        const float4 v = tbl[ib[l]];
        a0 += v.x; a1 += v.y; ap0 += v.z; ap1 += v.w;
    }

    #pragma unroll
    for (int off = 32; off > 0; off >>= 1) {
        a0  += __shfl_down(a0,  off, 64);
        a1  += __shfl_down(a1,  off, 64);
        ap0 += __shfl_down(ap0, off, 64);
        ap1 += __shfl_down(ap1, off, 64);
    }
    if (lane == 0) out[b] = ap0 / a0 + ap1 / a1;
}

extern "C" void kernel_launch(void* const* d_in, const int* in_sizes, int n_in,
                              void* d_out, int out_size, void* d_ws, size_t ws_size,
                              hipStream_t stream) {
    const int*   idx = (const int*)d_in[0];    // word_idxs [4096,200] int32
    const float* emb = (const float*)d_in[1];  // emb_table [100000,100] f32
    const float* wgt = (const float*)d_in[2];  // weights   [100,1] f32
    const float* att = (const float*)d_in[3];  // attend_u  [2,50] f32
    float* out = (float*)d_out;                // [4096] f32

    const int B     = out_size;                 // 4096
    const int L     = in_sizes[0] / B;          // 200
    const int vocab = in_sizes[1] / ED;         // 100000

    float4* tbl = (float4*)d_ws;                // 100000 * 16 B = 1.6 MB scratch

    row_stats_kernel<<<(vocab + ROWS - 1) / ROWS, 128, 0, stream>>>(emb, wgt, att, tbl, vocab);
    attend_kernel<<<(B + 3) / 4, 256, 0, stream>>>(idx, tbl, out, B, L);
}

// Round 4
// 94.707 us; speedup vs baseline: 1.0901x; 1.0901x over previous
//
#include <hip/hip_runtime.h>

// Problem constants (fixed by the reference):
//   B=4096, L=200, EMBEDDING_DIM=100, C=2 chunks of M=50, VOCAB=100000
constexpr int C_ = 2;
constexpr int M_ = 50;
constexpr int ED = 100;
constexpr float EPS = 1e-8f;

// ---------------------------------------------------------------------------
// Pass 1: per-vocab-row statistics: tbl[r] = (a0, a1, a0*dw0, a1*dw1).
// One thread per HALF-ROW (chunk) -> 200K threads = 782 full blocks
// (12 waves/CU) with 25 independent float2 loads each, so enough bytes are
// in flight to reach HBM rate (thread-per-row at 100K threads was
// latency-bound at ~25% of peak).
// ---------------------------------------------------------------------------
__global__ __launch_bounds__(256) void row_stats_kernel(
    const float* __restrict__ emb,   // [VOCAB, 100]
    const float* __restrict__ wgt,   // [100]
    const float* __restrict__ att,   // [100] = [2,50]
    float4*      __restrict__ tbl,   // [VOCAB]
    int vocab)
{
    __shared__ float2 s_uw[ED];   // (attend_u[e], weights[e])
    __shared__ float  s_su[C_];   // 1 / max(||u_c||, eps)

    const int t = threadIdx.x;
    if (t < ED) s_uw[t] = make_float2(att[t], wgt[t]);
    __syncthreads();
    if (t < C_) {
        float ss = 0.f;
        #pragma unroll
        for (int m = 0; m < M_; ++m) { float v = s_uw[t * M_ + m].x; ss += v * v; }
        s_su[t] = 1.0f / fmaxf(sqrtf(ss), EPS);
    }
    __syncthreads();

    const int h = blockIdx.x * 256 + t;          // half-row id
    if (h >= 2 * vocab) return;
    const int r = h >> 1;                         // row
    const int c = h & 1;                          // chunk (even lane=c0, odd=c1)

    // 25 independent float2 loads (chunk 1 starts at byte 200: float2-aligned).
    const float2* p = reinterpret_cast<const float2*>(emb + (long long)r * ED + c * M_);
    float sq = 0.f, du = 0.f, dw = 0.f;
    #pragma unroll
    for (int j = 0; j < M_ / 2; ++j) {
        const float2 v = p[j];
        const float2 uw0 = s_uw[c * M_ + 2 * j];      // 2-address broadcast: free
        const float2 uw1 = s_uw[c * M_ + 2 * j + 1];
        sq  = fmaf(v.x, v.x, sq);  sq = fmaf(v.y, v.y, sq);
        du  = fmaf(v.x, uw0.x, du); du = fmaf(v.y, uw1.x, du);
        dw  = fmaf(v.x, uw0.y, dw); dw = fmaf(v.y, uw1.y, dw);
    }
    const float cosv = du / fmaxf(sqrtf(sq), EPS) * s_su[c];
    const float a    = __expf(cosv);
    const float ap   = a * dw;

    // Pair lanes 2k (chunk0) / 2k+1 (chunk1) of the same row.
    const float a_o  = __shfl_xor(a,  1, 64);
    const float ap_o = __shfl_xor(ap, 1, 64);
    if (c == 0) tbl[r] = make_float4(a, a_o, ap, ap_o);
}

// ---------------------------------------------------------------------------
// Pass 2: one WAVE per batch element. out[b] = P0/A0 + P1/A1 over L gathered
// table entries (16 B each, 1.6 MB table is L2-resident). No __syncthreads.
// ---------------------------------------------------------------------------
__global__ __launch_bounds__(256) void attend_kernel(
    const int*    __restrict__ idx,  // [B, L]
    const float4* __restrict__ tbl,  // [VOCAB]
    float*        __restrict__ out,  // [B]
    int B, int L)
{
    const int wave = threadIdx.x >> 6;
    const int lane = threadIdx.x & 63;
    const int b    = blockIdx.x * 4 + wave;
    if (b >= B) return;

    const int* ib = idx + (long long)b * L;
    float a0 = 0.f, a1 = 0.f, ap0 = 0.f, ap1 = 0.f;
    #pragma unroll 4
    for (int l = lane; l < L; l += 64) {       // coalesced idx read, L2-hit gather
        const float4 v = tbl[ib[l]];
        a0 += v.x; a1 += v.y; ap0 += v.z; ap1 += v.w;
    }

    #pragma unroll
    for (int off = 32; off > 0; off >>= 1) {
        a0  += __shfl_down(a0,  off, 64);
        a1  += __shfl_down(a1,  off, 64);
        ap0 += __shfl_down(ap0, off, 64);
        ap1 += __shfl_down(ap1, off, 64);
    }
    if (lane == 0) out[b] = ap0 / a0 + ap1 / a1;
}

extern "C" void kernel_launch(void* const* d_in, const int* in_sizes, int n_in,
                              void* d_out, int out_size, void* d_ws, size_t ws_size,
                              hipStream_t stream) {
    const int*   idx = (const int*)d_in[0];    // word_idxs [4096,200] int32
    const float* emb = (const float*)d_in[1];  // emb_table [100000,100] f32
    const float* wgt = (const float*)d_in[2];  // weights   [100,1] f32
    const float* att = (const float*)d_in[3];  // attend_u  [2,50] f32
    float* out = (float*)d_out;                // [4096] f32

    const int B     = out_size;                 // 4096
    const int L     = in_sizes[0] / B;          // 200
    const int vocab = in_sizes[1] / ED;         // 100000

    float4* tbl = (float4*)d_ws;                // 100000 * 16 B = 1.6 MB scratch

    const int halves = 2 * vocab;
    row_stats_kernel<<<(halves + 255) / 256, 256, 0, stream>>>(emb, wgt, att, tbl, vocab);
    attend_kernel<<<(B + 3) / 4, 256, 0, stream>>>(idx, tbl, out, B, L);
}

// Round 5
// 93.335 us; speedup vs baseline: 1.1061x; 1.0147x over previous
//
#include <hip/hip_runtime.h>

// Problem constants (fixed by the reference):
//   B=4096, L=200, EMBEDDING_DIM=100, C=2 chunks of M=50, VOCAB=100000
constexpr int C_ = 2;
constexpr int M_ = 50;
constexpr int ED = 100;
constexpr float EPS = 1e-8f;

// tbl layout per row: (a0, a0*dw0, a1, a1*dw1)

// ---------------------------------------------------------------------------
// Pass 1: per-vocab-row statistics. Wave-uniform chunk mapping:
//   block = 128 threads = 2 waves; wave w handles chunk w of rows
//   [blockIdx*64, blockIdx*64+64). Each thread: 12 x float4 + 1 x float2
//   (chunk1 starts at byte 200; bytes 200-208 as float2, 208-400 as float4,
//   208 = 13*16 so alignment holds). 13 wide loads instead of 25 narrow ones
//   halves address-processing traffic; bytes are identical (one clean pass
//   over the 40 MB table).
// ---------------------------------------------------------------------------
__global__ __launch_bounds__(128) void row_stats_kernel(
    const float* __restrict__ emb,   // [VOCAB, 100]
    const float* __restrict__ wgt,   // [100]
    const float* __restrict__ att,   // [100] = [2,50]
    float*       __restrict__ tbl,   // [VOCAB * 4]
    int vocab)
{
    __shared__ float2 s_uw[ED];   // (attend_u[e], weights[e])
    __shared__ float  s_su[C_];   // 1 / max(||u_c||, eps)

    const int t = threadIdx.x;
    if (t < ED) s_uw[t] = make_float2(att[t], wgt[t]);
    __syncthreads();
    if (t < C_) {
        float ss = 0.f;
        #pragma unroll
        for (int m = 0; m < M_; ++m) { float v = s_uw[t * M_ + m].x; ss += v * v; }
        s_su[t] = 1.0f / fmaxf(sqrtf(ss), EPS);
    }
    __syncthreads();

    const int c    = t >> 6;                  // wave-uniform chunk id (0 or 1)
    const int lane = t & 63;
    const int r    = blockIdx.x * 64 + lane;  // row
    if (r >= vocab) return;

    const float* rowp = emb + (long long)r * ED + c * M_;  // 50 floats
    float x[M_];
    if (c == 0) {
        // bytes [0,192) as 12 float4, [192,200) as float2 -- all aligned
        #pragma unroll
        for (int j = 0; j < 12; ++j) {
            const float4 v = reinterpret_cast<const float4*>(rowp)[j];
            x[4*j] = v.x; x[4*j+1] = v.y; x[4*j+2] = v.z; x[4*j+3] = v.w;
        }
        const float2 v = *reinterpret_cast<const float2*>(rowp + 48);
        x[48] = v.x; x[49] = v.y;
    } else {
        // bytes [200,208) as float2, [208,400) as 12 float4 (208 % 16 == 0)
        const float2 v = *reinterpret_cast<const float2*>(rowp);
        x[0] = v.x; x[1] = v.y;
        #pragma unroll
        for (int j = 0; j < 12; ++j) {
            const float4 w = reinterpret_cast<const float4*>(rowp + 2)[j];
            x[2+4*j] = w.x; x[3+4*j] = w.y; x[4+4*j] = w.z; x[5+4*j] = w.w;
        }
    }

    float sq = 0.f, du = 0.f, dw = 0.f;
    #pragma unroll
    for (int e = 0; e < M_; ++e) {
        const float2 uw = s_uw[c * M_ + e];   // wave-uniform broadcast: free
        sq = fmaf(x[e], x[e], sq);
        du = fmaf(x[e], uw.x, du);
        dw = fmaf(x[e], uw.y, dw);
    }
    const float cosv = du / fmaxf(sqrtf(sq), EPS) * s_su[c];
    const float a    = __expf(cosv);
    // wave w writes its (a, a*dw) half of tbl[r] = (a0, a0*dw0, a1, a1*dw1)
    *reinterpret_cast<float2*>(tbl + 4 * r + 2 * c) = make_float2(a, a * dw);
}

// ---------------------------------------------------------------------------
// Pass 2: one WAVE per batch element. out[b] = P0/A0 + P1/A1 over L gathered
// table entries (16 B each, 1.6 MB table is L2/L3-resident). No __syncthreads.
// ---------------------------------------------------------------------------
__global__ __launch_bounds__(256) void attend_kernel(
    const int*    __restrict__ idx,  // [B, L]
    const float4* __restrict__ tbl,  // [VOCAB] as (a0, ap0, a1, ap1)
    float*        __restrict__ out,  // [B]
    int B, int L)
{
    const int wave = threadIdx.x >> 6;
    const int lane = threadIdx.x & 63;
    const int b    = blockIdx.x * 4 + wave;
    if (b >= B) return;

    const int* ib = idx + (long long)b * L;
    float a0 = 0.f, a1 = 0.f, ap0 = 0.f, ap1 = 0.f;
    #pragma unroll 4
    for (int l = lane; l < L; l += 64) {       // coalesced idx read, cached gather
        const float4 v = tbl[ib[l]];
        a0 += v.x; ap0 += v.y; a1 += v.z; ap1 += v.w;
    }

    #pragma unroll
    for (int off = 32; off > 0; off >>= 1) {
        a0  += __shfl_down(a0,  off, 64);
        a1  += __shfl_down(a1,  off, 64);
        ap0 += __shfl_down(ap0, off, 64);
        ap1 += __shfl_down(ap1, off, 64);
    }
    if (lane == 0) out[b] = ap0 / a0 + ap1 / a1;
}

extern "C" void kernel_launch(void* const* d_in, const int* in_sizes, int n_in,
                              void* d_out, int out_size, void* d_ws, size_t ws_size,
                              hipStream_t stream) {
    const int*   idx = (const int*)d_in[0];    // word_idxs [4096,200] int32
    const float* emb = (const float*)d_in[1];  // emb_table [100000,100] f32
    const float* wgt = (const float*)d_in[2];  // weights   [100,1] f32
    const float* att = (const float*)d_in[3];  // attend_u  [2,50] f32
    float* out = (float*)d_out;                // [4096] f32

    const int B     = out_size;                 // 4096
    const int L     = in_sizes[0] / B;          // 200
    const int vocab = in_sizes[1] / ED;         // 100000

    float* tbl = (float*)d_ws;                  // 100000 * 16 B = 1.6 MB scratch

    row_stats_kernel<<<(vocab + 63) / 64, 128, 0, stream>>>(emb, wgt, att, tbl, vocab);
    attend_kernel<<<(B + 3) / 4, 256, 0, stream>>>(idx, (const float4*)tbl, out, B, L);
}